// Round 17
// baseline (34.957 us; speedup 1.0000x reference)
//
#include <hip/hip_runtime.h>
#include <math.h>

#define LAT_CONST  ((float)(5.0 * 0.03 / 200.0 + 0.06))   // 0.06075
#define GRAD_CONST ((float)(1.0 / 0.06))                  // 16.666666...
#define SEND_CONST ((float)(2.0 / 3.0))                   // 0.666666...

// Wide coarse table (step 1, LDS bf16 pairs): 512 cells over [-24, 24].
#define NWC  512
#define LOW_ (-24.f)
#define HWC  (48.f / (float)NWC)
#define IHWC ((float)NWC / 48.f)              // 10.6667
#define CWC  (24.f * IHWC)                    // 256
// Narrow coarse table (steps 2..10, LDS bf16 pairs): 128 cells over [-6.25,1.25].
#define NCC  128
#define LO2  (-6.25f)
#define HI2  (1.25f)
#define H2C  ((HI2 - LO2) / (float)NCC)
#define IHC  ((float)NCC / (HI2 - LO2))       // 17.0667
#define CC   (-LO2 * IHC)                     // 106.667

#define WSZ 520      // wide f32 entries built (rows uses 0..513)
#define CSZ 136      // narrow f32 entries built (rows uses 0..129)

typedef unsigned int u32;

__device__ __forceinline__ u32 bfpack(float a, float b) {
    u32 ua = __float_as_uint(a), ub = __float_as_uint(b);
    ua = (ua + 0x7fffu + ((ua >> 16) & 1u)) >> 16;          // RNE to bf16
    ub = (ub + 0x7fffu + ((ub >> 16) & 1u)) & 0xffff0000u;  // RNE, keep high half
    return (ua & 0xffffu) | ub;
}

__device__ __forceinline__ float lerp_pk(u32 u, float fr) {
    float e0 = __uint_as_float(u << 16);
    float e1 = __uint_as_float(u & 0xffff0000u);
    return fmaf(e1 - e0, fr, e0);
}

// ---------------- Kernel 1: build both small f32 tables (656 entries) -------
__global__ __launch_bounds__(512)
void build_table_kernel(const float* __restrict__ W1, const float* __restrict__ b1,
                        const float* __restrict__ W2, const float* __restrict__ b2,
                        const float* __restrict__ W3, const float* __restrict__ b3,
                        float* __restrict__ g1, float* __restrict__ g2)
{
    __shared__ float pl[8][64];

    const int lane = threadIdx.x & 63;
    const int w    = threadIdx.x >> 6;                // 0..7
    const int i    = blockIdx.x * 64 + lane;
    const int ie   = (i < WSZ + CSZ) ? i : (WSZ + CSZ - 1);

    float t;
    if (ie < WSZ) t = LOW_ + (float)ie * HWC;
    else          t = LO2 + (float)(ie - WSZ) * H2C;

    float x4 = t + LAT_CONST;
    float x5 = t * SEND_CONST;
    float x3 = x4 * GRAD_CONST;

    float h1v[64];
#pragma unroll
    for (int j = 0; j < 64; ++j) {
        float acc = b1[j];
        acc = fmaf(x3, W1[j],       acc);
        acc = fmaf(x4, W1[64 + j],  acc);
        acc = fmaf(x5, W1[128 + j], acc);
        h1v[j] = fmaxf(acc, 0.f);
    }

    const int j0 = w * 8;
    float acc[8];
#pragma unroll
    for (int u = 0; u < 8; ++u) acc[u] = b2[j0 + u];
#pragma unroll
    for (int k = 0; k < 64; ++k) {
        const float* __restrict__ w2r = W2 + k * 64 + j0;
#pragma unroll
        for (int u = 0; u < 8; ++u)
            acc[u] = fmaf(h1v[k], w2r[u], acc[u]);
    }
    float partial = 0.f;
#pragma unroll
    for (int u = 0; u < 8; ++u)
        partial = fmaf(fmaxf(acc[u], 0.f), W3[j0 + u], partial);

    pl[w][lane] = partial;
    __syncthreads();

    if (w == 0 && i < WSZ + CSZ) {
        float logit = b3[0] + (((pl[0][lane] + pl[1][lane]) + (pl[2][lane] + pl[3][lane]))
                             + ((pl[4][lane] + pl[5][lane]) + (pl[6][lane] + pl[7][lane])));
        float g = 1.f / (1.f + expf(-logit));
        if (i < WSZ) g1[i] = g;
        else         g2[i - WSZ] = g;
    }
}

// ---------------- Kernel 2: 3-buffer single-barrier pipelined row update ----
// Per barrier-to-barrier segment: {stage DMA(c+1) || compute(c) || store(c-1)}
// -> VMEM and LDS pipes both busy in EVERY segment (vs alternating phases).
// LDS = 3*7168 + 2.6 KB = 23.7 KB -> 6 blocks/CU (24 waves).
#define CHUNK 256
#define BLOCK 256
#define MAXBLK 1536       // 6 blocks/CU * 256 CU

typedef __attribute__((address_space(3))) u32 lds_u32_t;
typedef __attribute__((address_space(1))) const u32 glb_u32_t;

__device__ __forceinline__ void gload16(const void* g, void* l) {
    __builtin_amdgcn_global_load_lds((glb_u32_t*)g, (lds_u32_t*)l, 16, 0, 0);
}
__device__ __forceinline__ void gload4(const void* g, void* l) {
    __builtin_amdgcn_global_load_lds((glb_u32_t*)g, (lds_u32_t*)l, 4, 0, 0);
}

__global__ __launch_bounds__(BLOCK)
void rows_kernel(const float* __restrict__ x, const float* __restrict__ g1,
                 const float* __restrict__ g2, float* __restrict__ out,
                 int B, int nChunks, int grid)
{
    __shared__ u32 tcw[NWC + 4];                       // 2064 B
    __shared__ u32 tcn[NCC + 4];                       // 528 B
    __shared__ __align__(16) float buf[3][CHUNK * 7];  // 21504 B

    const int tid = threadIdx.x;
    const long long b = blockIdx.x;
    const int cb = (int)(b * (long long)nChunks / grid);
    const int ce = (int)((b + 1) * (long long)nChunks / grid);

    // Prologue: stage first chunk into buf[0] (lands under table packing).
    {
        int rows0 = min(CHUNK, B - cb * CHUNK);
        int nfl0  = rows0 * 7;
        int nf40  = nfl0 >> 2;
        const float* src = x + (size_t)cb * CHUNK * 7;
        for (int i = tid; i < nf40; i += BLOCK)
            gload16((const float4*)src + i, &buf[0][i * 4]);
        for (int i = (nf40 << 2) + tid; i < nfl0; i += BLOCK)
            gload4(src + i, &buf[0][i]);
    }
    // Pack both coarse tables from the L2-hot f32 builds.
    for (int i = tid; i < NWC + 2; i += BLOCK) tcw[i] = bfpack(g1[i], g1[i + 1]);
    for (int i = tid; i < NCC + 2; i += BLOCK) tcn[i] = bfpack(g2[i], g2[i + 1]);
    __syncthreads();   // tables ready + first DMA drained

    float* bC = buf[0];   // compute buffer (chunk c)
    float* bS = buf[1];   // stage target  (chunk c+1)
    float* bP = buf[2];   // store source  (chunk c-1)

    for (int c = cb; c < ce; ++c) {
        // --- stage(c+1): issue DMA (lands during this segment + next) ---
        if (c + 1 < ce) {
            int rowsN = min(CHUNK, B - (c + 1) * CHUNK);
            int nflN  = rowsN * 7;
            int nf4N  = nflN >> 2;
            const float* src = x + (size_t)(c + 1) * CHUNK * 7;
            for (int i = tid; i < nf4N; i += BLOCK)
                gload16((const float4*)src + i, &bS[i * 4]);
            for (int i = (nf4N << 2) + tid; i < nflN; i += BLOCK)
                gload4(src + i, &bS[i]);
        }

        // --- compute(c): all-LDS gather chain (interleaves with VMEM above) ---
        {
            int rows = min(CHUNK, B - c * CHUNK);
            for (int r = tid; r < rows; r += BLOCK) {
                float* row = bC + r * 7;               // stride 7: 2/bank, free
                float x0 = row[0], x2 = row[2], x6 = row[6];
                float f = (x6 <= 0.f) ? (x6 + 1.f) : (1.f - x6);
                {   // step 1: wide coarse table
                    float p = fmaf(x2, f * IHWC, CWC);
                    p = fminf(fmaxf(p, 0.f), (float)NWC);
                    int idx = (int)p; float fr = p - (float)idx;
                    x2 = lerp_pk(tcw[idx], fr);
                }
                float afc = f * IHC;
#pragma unroll
                for (int s = 0; s < 8; ++s) {          // steps 2..9
                    float p = fmaf(x2, afc, CC);
                    p = fminf(fmaxf(p, 0.f), (float)NCC);
                    int idx = (int)p; float fr = p - (float)idx;
                    x2 = lerp_pk(tcn[idx], fr);
                }
                float t = x2 * f;                      // step 10 + outputs
                float p = fmaf(t, IHC, CC);
                p = fminf(fmaxf(p, 0.f), (float)NCC);
                int idx = (int)p; float fr = p - (float)idx;
                float x2f = lerp_pk(tcn[idx], fr);
                float x4 = t + LAT_CONST;
                row[0] = x0 + 10.f;                    // 10 steps of +1
                row[2] = x2f;
                row[3] = x4 * GRAD_CONST;
                row[4] = x4;
                row[5] = t * SEND_CONST;               // cols 1,6 pass through
            }
        }

        // --- store(c-1): coalesced f4 (retires before its buffer re-staged) ---
        if (c > cb) {
            int rowsP = min(CHUNK, B - (c - 1) * CHUNK);
            int nflP  = rowsP * 7;
            int nf4P  = nflP >> 2;
            float* dst = out + (size_t)(c - 1) * CHUNK * 7;
            const float4* s4 = (const float4*)bP;
            for (int i = tid; i < nf4P; i += BLOCK) ((float4*)dst)[i] = s4[i];
            for (int i = (nf4P << 2) + tid; i < nflP; i += BLOCK) dst[i] = bP[i];
        }

        __syncthreads();   // drains DMA(c+1) + stores(c-1); orders buffer reuse
        float* tmp = bP; bP = bC; bC = bS; bS = tmp;
    }

    // Epilogue: store the last computed chunk (now in bP after rotation).
    {
        int c = ce - 1;
        int rowsP = min(CHUNK, B - c * CHUNK);
        int nflP  = rowsP * 7;
        int nf4P  = nflP >> 2;
        float* dst = out + (size_t)c * CHUNK * 7;
        const float4* s4 = (const float4*)bP;
        for (int i = tid; i < nf4P; i += BLOCK) ((float4*)dst)[i] = s4[i];
        for (int i = (nf4P << 2) + tid; i < nflP; i += BLOCK) dst[i] = bP[i];
    }
}

static inline size_t align16h(size_t v) { return (v + 15) & ~(size_t)15; }

extern "C" void kernel_launch(void* const* d_in, const int* in_sizes, int n_in,
                              void* d_out, int out_size, void* d_ws, size_t ws_size,
                              hipStream_t stream)
{
    const float* x  = (const float*)d_in[0];
    const float* W1 = (const float*)d_in[1];
    const float* b1 = (const float*)d_in[2];
    const float* W2 = (const float*)d_in[3];
    const float* b2 = (const float*)d_in[4];
    const float* W3 = (const float*)d_in[5];
    const float* b3 = (const float*)d_in[6];
    float* out = (float*)d_out;

    int B = in_sizes[0] / 7;

    // ws: [g1 f32 WSZ][g2 f32 CSZ]
    char* ws = (char*)d_ws;
    float* g1 = (float*)ws;
    float* g2 = (float*)(ws + align16h((size_t)WSZ * 4));

    int nChunks = (B + CHUNK - 1) / CHUNK;
    int grid    = (nChunks < MAXBLK) ? nChunks : MAXBLK;

    hipLaunchKernelGGL(build_table_kernel, dim3((WSZ + CSZ + 63) / 64), dim3(512), 0, stream,
                       W1, b1, W2, b2, W3, b3, g1, g2);
    hipLaunchKernelGGL(rows_kernel, dim3(grid), dim3(BLOCK), 0, stream,
                       x, g1, g2, out, B, nChunks, grid);
}